// Round 5
// baseline (21807.224 us; speedup 1.0000x reference)
//
#include <hip/hip_runtime.h>
#include <hip/hip_bf16.h>
#include <stdint.h>

typedef unsigned short u16;
typedef unsigned int u32;
typedef unsigned long long u64;
typedef __attribute__((ext_vector_type(8))) short short8;
typedef __attribute__((ext_vector_type(4))) float f32x4;
typedef __attribute__((ext_vector_type(2))) float f32x2;
typedef __attribute__((ext_vector_type(4))) unsigned short u16x4;

__device__ __forceinline__ float bf2f(u16 h) {
    union { u32 u; float f; } c; c.u = ((u32)h) << 16; return c.f;
}
__device__ __forceinline__ u16 f2bf(float f) {
    union { float f; u32 u; } c; c.f = f;
    u32 u = c.u;
    return (u16)((u + 0x7fffu + ((u >> 16) & 1u)) >> 16);
}

// fast tanh: 1 - 2/(exp2(2*log2e*|x|)+1), sign restored. inf-safe (p=inf -> 1).
__device__ __forceinline__ float fast_tanh(float x) {
    float ax = __builtin_fabsf(x);
    float arg = ax * 2.8853900817779268f;  // 2*log2(e)
    float p;
    asm("v_exp_f32 %0, %1" : "=v"(p) : "v"(arg));
    float q = p + 1.f;
    float r;
    asm("v_rcp_f32 %0, %1" : "=v"(r) : "v"(q));
    float t = 1.f - 2.f * r;
    return __builtin_copysignf(t, x);
}

// ---------------------------------------------------------------------------
// init: every packed u32 in BOTH exchange buffers (fast||slow contiguous,
// 512KB total) gets tag bit16 = 1 (first-gen tag is 0 -> consumers spin until
// real data lands). 128 blk x 256 thr x 16B = 512KB. Block 0 zeroes xcd_tbl.
__global__ void k_init(u32* h_exf, int* xcd_tbl) {
    uint4 v;
    v.x = 0x00010000u; v.y = 0x00010000u; v.z = 0x00010000u; v.w = 0x00010000u;
    ((uint4*)h_exf)[blockIdx.x * 256 + threadIdx.x] = v;
    if (blockIdx.x == 0 && threadIdx.x < 64) xcd_tbl[threadIdx.x] = 0;
}

// cvec[i] = sum_k W_y[i,k]*b_out[k];  biasE[i] = cvec[i] + b_in[i] + b_y[i]
__global__ void k_c(const float* __restrict__ Wy, const float* __restrict__ bout,
                    const float* __restrict__ bin, const float* __restrict__ by,
                    float* __restrict__ cvec, float* __restrict__ biasE) {
    int i = blockIdx.x * 64 + threadIdx.x;
    const float* wr = Wy + (size_t)i * 512;
    float s = 0.f;
    for (int k = 0; k < 512; ++k) s += wr[k] * bout[k];
    cvec[i] = s;
    biasE[i] = s + bin[i] + by[i];
}

// z0mc[b,i] = sum_k ll[b,k]*W_y[i,k] - cvec[i]
__global__ __launch_bounds__(512) void k_z0(const float* __restrict__ ll,
                                            const float* __restrict__ Wy,
                                            const float* __restrict__ cvec,
                                            float* __restrict__ z0mc) {
    __shared__ float lls[512];
    int b = blockIdx.x, i = threadIdx.x;
    lls[i] = ll[b * 512 + i];
    __syncthreads();
    const float* wr = Wy + (size_t)i * 512;
    float s = 0.f;
    for (int k = 0; k < 512; ++k) s += wr[k] * lls[k];
    z0mc[(size_t)b * 512 + i] = s - cvec[i];
}

// split fp32 [512*512] -> hi/lo bf16 planes
__global__ __launch_bounds__(256) void k_split(const float* __restrict__ in,
                                               u16* __restrict__ hi,
                                               u16* __restrict__ lo) {
    int i = blockIdx.x * 256 + threadIdx.x;
    float v = in[i];
    u16 h = f2bf(v);
    hi[i] = h;
    lo[i] = f2bf(v - bf2f(h));
}

// transpose+split fp32 512x512: out[j,k] = in[k,j] as hi/lo bf16 planes
__global__ __launch_bounds__(256) void k_tsplit(const float* __restrict__ in,
                                                u16* __restrict__ hi,
                                                u16* __restrict__ lo) {
    __shared__ float tile[32][33];
    int bx = blockIdx.x, by = blockIdx.y;
    int tx = threadIdx.x & 31, ty = threadIdx.x >> 5;  // 32 x 8
    for (int i = 0; i < 32; i += 8)
        tile[ty + i][tx] = in[(size_t)(by * 32 + ty + i) * 512 + bx * 32 + tx];
    __syncthreads();
    for (int i = 0; i < 32; i += 8) {
        float v = tile[tx][ty + i];
        size_t idx = (size_t)(bx * 32 + ty + i) * 512 + by * 32 + tx;
        u16 h = f2bf(v);
        hi[idx] = h;
        lo[idx] = f2bf(v - bf2f(h));
    }
}

// ---------------------------------------------------------------------------
// gemm3: C[row,col] = sum_k A[row,k]*B[col,k] (+bias), B as hi/lo bf16 planes.
// ---------------------------------------------------------------------------
__global__ __launch_bounds__(256) void gemm3(
    const void* __restrict__ Aptr, int a_fp32,
    const u16* __restrict__ Bhi, const u16* __restrict__ Blo,
    u16* __restrict__ out_hi, u16* __restrict__ out_lo,
    float* __restrict__ out_f,
    const float* __restrict__ bias, int mode) {
    __shared__ u16 AsHi[128 * 32];
    __shared__ u16 AsLo[128 * 32];
    __shared__ u16 BsHi[128 * 32];
    __shared__ u16 BsLo[128 * 32];
    const int tid = threadIdx.x;
    const int lane = tid & 63;
    const int w = tid >> 6;
    const int wm = w & 1, wn = w >> 1;
    const int quad = lane >> 4, l15 = lane & 15;
    const int tx = blockIdx.x, tn = blockIdx.y;

    f32x4 acc[4][4];
    f32x4 zero4 = {0.f, 0.f, 0.f, 0.f};
#pragma unroll
    for (int i = 0; i < 4; ++i)
#pragma unroll
        for (int j = 0; j < 4; ++j) acc[i][j] = zero4;

    const float* Af = (const float*)Aptr;
    const u16* Ab = (const u16*)Aptr;
    const int s0 = tid, s1 = tid + 256;

    for (int kk = 0; kk < 16; ++kk) {
        const uint4* BgH = (const uint4*)(Bhi + (size_t)tn * 128 * 512 + kk * 32);
        const uint4* BgL = (const uint4*)(Blo + (size_t)tn * 128 * 512 + kk * 32);
        uint4 bh0 = BgH[(s0 >> 2) * 64 + (s0 & 3)];
        uint4 bh1 = BgH[(s1 >> 2) * 64 + (s1 & 3)];
        uint4 bl0 = BgL[(s0 >> 2) * 64 + (s0 & 3)];
        uint4 bl1 = BgL[(s1 >> 2) * 64 + (s1 & 3)];
        f32x4 av[4];
        uint4 ab0, ab1;
        if (a_fp32) {
            const float* Agf = Af + (size_t)tx * 128 * 512 + kk * 32;
#pragma unroll
            for (int p = 0; p < 4; ++p) {
                int f = tid + p * 256;
                av[p] = *(const f32x4*)(Agf + (f >> 3) * 512 + (f & 7) * 4);
            }
        } else {
            const uint4* Ag = (const uint4*)(Ab + (size_t)tx * 128 * 512 + kk * 32);
            ab0 = Ag[(s0 >> 2) * 64 + (s0 & 3)];
            ab1 = Ag[(s1 >> 2) * 64 + (s1 & 3)];
        }
        __syncthreads();
        ((uint4*)BsHi)[s0] = bh0; ((uint4*)BsHi)[s1] = bh1;
        ((uint4*)BsLo)[s0] = bl0; ((uint4*)BsLo)[s1] = bl1;
        if (a_fp32) {
#pragma unroll
            for (int p = 0; p < 4; ++p) {
                int f = tid + p * 256;
                u16x4 hi4, lo4;
#pragma unroll
                for (int j = 0; j < 4; ++j) {
                    float v = av[p][j];
                    u16 hh = f2bf(v);
                    hi4[j] = hh;
                    lo4[j] = f2bf(v - bf2f(hh));
                }
                int off = (f >> 3) * 32 + (f & 7) * 4;
                *(u16x4*)(AsHi + off) = hi4;
                *(u16x4*)(AsLo + off) = lo4;
            }
        } else {
            ((uint4*)AsHi)[s0] = ab0;
            ((uint4*)AsHi)[s1] = ab1;
        }
        __syncthreads();

        short8 afh[4], afl[4], bfh[4], bfl[4];
#pragma unroll
        for (int mi = 0; mi < 4; ++mi) {
            afh[mi] = *(const short8*)(AsHi + (wm * 64 + mi * 16 + l15) * 32 + quad * 8);
            if (a_fp32)
                afl[mi] = *(const short8*)(AsLo + (wm * 64 + mi * 16 + l15) * 32 + quad * 8);
        }
#pragma unroll
        for (int ni = 0; ni < 4; ++ni) {
            bfh[ni] = *(const short8*)(BsHi + (wn * 64 + ni * 16 + l15) * 32 + quad * 8);
            bfl[ni] = *(const short8*)(BsLo + (wn * 64 + ni * 16 + l15) * 32 + quad * 8);
        }
#pragma unroll
        for (int mi = 0; mi < 4; ++mi)
#pragma unroll
            for (int ni = 0; ni < 4; ++ni) {
                acc[mi][ni] = __builtin_amdgcn_mfma_f32_16x16x32_bf16(
                    afh[mi], bfh[ni], acc[mi][ni], 0, 0, 0);
                acc[mi][ni] = __builtin_amdgcn_mfma_f32_16x16x32_bf16(
                    afh[mi], bfl[ni], acc[mi][ni], 0, 0, 0);
                if (a_fp32)
                    acc[mi][ni] = __builtin_amdgcn_mfma_f32_16x16x32_bf16(
                        afl[mi], bfh[ni], acc[mi][ni], 0, 0, 0);
            }
    }

#pragma unroll
    for (int mi = 0; mi < 4; ++mi) {
#pragma unroll
        for (int ni = 0; ni < 4; ++ni) {
            int col = tn * 128 + wn * 64 + ni * 16 + l15;
            float bv = (mode == 1) ? bias[col] : 0.f;
#pragma unroll
            for (int r = 0; r < 4; ++r) {
                int row = tx * 128 + wm * 64 + mi * 16 + quad * 4 + r;
                float v = acc[mi][ni][r] + bv;
                size_t idx = (size_t)row * 512 + col;
                if (mode == 0) {
                    u16 hi = f2bf(v);
                    out_hi[idx] = hi;
                    out_lo[idx] = f2bf(v - bf2f(hi));
                } else {
                    out_f[idx] = v;
                }
            }
        }
    }
}

// ---------------------------------------------------------------------------
// Scan, round 5: XCD-LOCAL EXCHANGE, HANG-PROOF.
//
// Geometry: 8 groups(g=blk&7) x 8 batch rows; 8 slices(s=blk>>3) x 64 dims.
// Round-robin blk->XCD puts a group's 8 WGs on one XCD; they exchange h via
// the XCD's physically-shared L2 (sc0 store = write-through to L2; sc0 load =
// L1-bypass, serviced at L2; RT ~250cyc vs ~2000cyc MALL RT that agent-scope
// pays — the per-step floor of rounds 0-3).
//
// Hang-proofing (R4 died; both its unbounded spins are now bounded):
//  - DUAL-PUBLISH: every u64 is stored to the fast buffer (sc0) AND the slow
//    buffer (agent scope, MALL-coherent). Fire-and-forget, off critical path.
//  - Fast consumers poll the fast buffer with the tag-verified bulk load
//    itself (bounded, 4096 iters); on timeout they LATCH use_fast=false and
//    fall through to the round-2-PROVEN agent-scope protocol on the slow
//    buffer (unbounded but proven live: producers always publish there).
//  - Discovery spin over xcd_tbl is bounded; unknown id -> slow path.
//  - Mixed fast/slow waves are fine: both buffers carry identical payloads;
//    tags gate every word; the skew-2 dataflow-overwrite argument (publish
//    t+1 only after consuming t, WG-joined at B1) is buffer-agnostic.
//  - Compile risk: R4's 16-output mega-asm split into two self-contained
//    8-load asms (internal s_waitcnt -> outputs valid at asm end, no
//    hoist/spill hazard on in-flight asm outputs).
//
// Per WG: M slice [64 dims x 512] hi/lo in VGPRs (128/lane); wave w owns
// k-range [128w,128w+128): 4 ksteps x 4 n-tiles x 3 products = 48 MFMA;
// k-partials reduced via LDS (zp). MFMA m=16 with batch rows duplicated
// (l15&7); quad>=2 outputs discarded. e prefetched one step ahead.
// ---------------------------------------------------------------------------
__global__ __launch_bounds__(256, 1) void k_scan(
    const u16* __restrict__ Mhi, const u16* __restrict__ Mlo,
    float* e_io,                   // [b*512+t][512] fp32: e in, h out
    const float* __restrict__ z0mc,
    u32* h_exf,                    // fast buf [2][8][8*512] u32, tagged
    u32* h_exs,                    // slow buf, same layout
    int* xcd_tbl)                  // [64] discovery table (k_init zeroes)
{
    __shared__ float zp[4 * 512];  // [w][row 8][dim 64]
    __shared__ int ids[64];

    const int tid = threadIdx.x;
    const int lane = tid & 63, w = tid >> 6;
    const int quad = lane >> 4, l15 = lane & 15;
    const int g = blockIdx.x & 7, s = blockIdx.x >> 3;

    // ---- XCD discovery & path selection (one-time, bounded) ----
    u32 xcc;
    asm volatile("s_getreg_b32 %0, hwreg(HW_REG_XCC_ID)" : "=s"(xcc));
    if (tid == 0)
        __hip_atomic_store(&xcd_tbl[blockIdx.x], (int)xcc + 1,
                           __ATOMIC_RELAXED, __HIP_MEMORY_SCOPE_AGENT);
    if (tid < 64) {
        int v = 0;
        for (int it = 0; it < 65536; ++it) {
            v = __hip_atomic_load(&xcd_tbl[tid], __ATOMIC_RELAXED,
                                  __HIP_MEMORY_SCOPE_AGENT);
            if (v != 0) break;
            __builtin_amdgcn_s_sleep(2);
        }
        ids[tid] = v;  // 0 => unknown -> slow path
    }
    __syncthreads();
    bool use_fast;
    {
        int ref = ids[g];
        bool eq = (ref != 0);
#pragma unroll
        for (int i = 1; i < 8; ++i) eq &= (ids[g + 8 * i] == ref);
        bool dist = false;
        for (int i = 0; i < 64; ++i) dist |= (ids[i] != ids[0]);
        use_fast = eq && dist;  // dist: guard against constant/broken XCC_ID
    }

    // ---- register-resident M fragments ----
    // lane holds M[s*64 + nt*16 + l15][w*128 + ks*32 + quad*8 + j]
    short8 mf[4][4][2];  // [nt][ks][plane] = 128 VGPR/lane
#pragma unroll
    for (int nt = 0; nt < 4; ++nt)
#pragma unroll
        for (int ks = 0; ks < 4; ++ks) {
            size_t off = ((size_t)(s * 64 + nt * 16 + l15)) * 512 +
                         (w * 128 + ks * 32 + quad * 8);
            mf[nt][ks][0] = *(const short8*)(Mhi + off);
            mf[nt][ks][1] = *(const short8*)(Mlo + off);
        }

    const int row = tid >> 5;       // 0..7 batch row within group
    const int c0 = (tid & 31) * 2;  // 0..62 dim pair within slice
    const int bb = g * 8 + row;
    // lane's u64 base within a group-buffer (u32 layout [row 8][dim 512])
    const size_t lbase = (size_t)((l15 & 7) * 256 + w * 64 + quad * 4);
    const int cks = (l15 >> 1) & 3;  // canary kstep (slow path)

    size_t eidx = ((size_t)bb * 512) * 512 + s * 64 + c0;
    f32x2 ecur = *(const f32x2*)(e_io + eidx);

    const u64 TAGMASK = (1ull << 16) | (1ull << 48);
    u64 d[16];  // [ks*4 + j], all statically indexed

    // 8 loads (2 ksteps) from pb, L1-bypass (sc0), self-contained wait.
    auto load8f = [&](u64* dd, const u64* pb) {
        asm volatile(
            "global_load_dwordx2 %0, %8, off sc0\n\t"
            "global_load_dwordx2 %1, %8, off offset:8 sc0\n\t"
            "global_load_dwordx2 %2, %8, off offset:16 sc0\n\t"
            "global_load_dwordx2 %3, %8, off offset:24 sc0\n\t"
            "global_load_dwordx2 %4, %8, off offset:128 sc0\n\t"
            "global_load_dwordx2 %5, %8, off offset:136 sc0\n\t"
            "global_load_dwordx2 %6, %8, off offset:144 sc0\n\t"
            "global_load_dwordx2 %7, %8, off offset:152 sc0\n\t"
            "s_waitcnt vmcnt(0)"
            : "=&v"(dd[0]), "=&v"(dd[1]), "=&v"(dd[2]), "=&v"(dd[3]),
              "=&v"(dd[4]), "=&v"(dd[5]), "=&v"(dd[6]), "=&v"(dd[7])
            : "v"(pb)
            : "memory");
    };
    auto bulk_slow = [&](const u64* pb) {
#pragma unroll
        for (int k = 0; k < 16; ++k)
            d[k] = __hip_atomic_load(pb + (k >> 2) * 16 + (k & 3),
                                     __ATOMIC_RELAXED, __HIP_MEMORY_SCOPE_AGENT);
    };
    auto tags_ok = [&](u64 tv) {
        u64 bad = 0;
#pragma unroll
        for (int k = 0; k < 16; ++k) bad |= (d[k] ^ tv) & TAGMASK;
        return __all(bad == 0);
    };

#pragma unroll 1
    for (int t = 0; t < 512; ++t) {
        if (t > 0) {
            const size_t gb = (size_t)(((t - 1) & 1) * 8 + g) * 2048;
            const u64 tv = (((t - 1) >> 1) & 1) ? TAGMASK : 0ull;
            bool got = false;
            if (use_fast) {
                const u64* pb = (const u64*)h_exf + gb + lbase;
                for (int it = 0; it < 4096; ++it) {
                    load8f(&d[0], pb);
                    load8f(&d[8], pb + 32);
                    if (tags_ok(tv)) { got = true; break; }
                }
                if (!got) use_fast = false;  // latch: sc0 model failed
            }
            if (!got) {
                // round-2-proven slow path (unbounded; producers always
                // publish to the slow buffer)
                const u64* pb = (const u64*)h_exs + gb + lbase;
                const u64* pc = pb + (size_t)cks * 16;
                for (;;) {
                    u64 c = __hip_atomic_load(pc, __ATOMIC_RELAXED,
                                              __HIP_MEMORY_SCOPE_AGENT);
                    if (__all(((c ^ tv) & TAGMASK) == 0)) break;
                }
                bulk_slow(pb);
                while (!tags_ok(tv)) bulk_slow(pb);
            }
            // ---- MFMA: z[16(8 real) rows][64 dims], this wave's k-quarter
            f32x4 acc[4];
            f32x4 zero4 = {0.f, 0.f, 0.f, 0.f};
#pragma unroll
            for (int nt = 0; nt < 4; ++nt) acc[nt] = zero4;
#pragma unroll
            for (int ks = 0; ks < 4; ++ks) {
                u32 x0 = (u32)d[4 * ks + 0], x1 = (u32)(d[4 * ks + 0] >> 32);
                u32 x2 = (u32)d[4 * ks + 1], x3 = (u32)(d[4 * ks + 1] >> 32);
                u32 x4 = (u32)d[4 * ks + 2], x5 = (u32)(d[4 * ks + 2] >> 32);
                u32 x6 = (u32)d[4 * ks + 3], x7 = (u32)(d[4 * ks + 3] >> 32);
                union { short8 s8; u32 u[4]; } hi_, lo_;
#if __has_builtin(__builtin_amdgcn_perm)
                hi_.u[0] = __builtin_amdgcn_perm(x1, x0, 0x05040100u);
                hi_.u[1] = __builtin_amdgcn_perm(x3, x2, 0x05040100u);
                hi_.u[2] = __builtin_amdgcn_perm(x5, x4, 0x05040100u);
                hi_.u[3] = __builtin_amdgcn_perm(x7, x6, 0x05040100u);
                lo_.u[0] = __builtin_amdgcn_perm(x1, x0, 0x07060302u);
                lo_.u[1] = __builtin_amdgcn_perm(x3, x2, 0x07060302u);
                lo_.u[2] = __builtin_amdgcn_perm(x5, x4, 0x07060302u);
                lo_.u[3] = __builtin_amdgcn_perm(x7, x6, 0x07060302u);
#else
                hi_.u[0] = ((x1 & 0xffffu) << 16) | (x0 & 0xffffu);
                hi_.u[1] = ((x3 & 0xffffu) << 16) | (x2 & 0xffffu);
                hi_.u[2] = ((x5 & 0xffffu) << 16) | (x4 & 0xffffu);
                hi_.u[3] = ((x7 & 0xffffu) << 16) | (x6 & 0xffffu);
                lo_.u[0] = (x1 & 0xffff0000u) | (x0 >> 16);
                lo_.u[1] = (x3 & 0xffff0000u) | (x2 >> 16);
                lo_.u[2] = (x5 & 0xffff0000u) | (x4 >> 16);
                lo_.u[3] = (x7 & 0xffff0000u) | (x6 >> 16);
#endif
#pragma unroll
                for (int nt = 0; nt < 4; ++nt) {
                    acc[nt] = __builtin_amdgcn_mfma_f32_16x16x32_bf16(
                        hi_.s8, mf[nt][ks][0], acc[nt], 0, 0, 0);
                    acc[nt] = __builtin_amdgcn_mfma_f32_16x16x32_bf16(
                        lo_.s8, mf[nt][ks][0], acc[nt], 0, 0, 0);
                    acc[nt] = __builtin_amdgcn_mfma_f32_16x16x32_bf16(
                        hi_.s8, mf[nt][ks][1], acc[nt], 0, 0, 0);
                }
            }
            if (quad < 2) {
#pragma unroll
                for (int nt = 0; nt < 4; ++nt)
#pragma unroll
                    for (int r = 0; r < 4; ++r)
                        zp[w * 512 + (quad * 4 + r) * 64 + nt * 16 + l15] =
                            acc[nt][r];
            }
        }
        // B1: zp ready (lgkm only; no vmem drain -> e-prefetch stays live)
        asm volatile("s_waitcnt lgkmcnt(0)" ::: "memory");
        __builtin_amdgcn_s_barrier();
        asm volatile("" ::: "memory");

        {
            float zv0, zv1;
            if (t == 0) {
                f32x2 zz = *(const f32x2*)(z0mc + (size_t)bb * 512 + s * 64 + c0);
                zv0 = zz[0]; zv1 = zz[1];
            } else {
                f32x2 s0 = *(const f32x2*)(zp + 0 * 512 + row * 64 + c0);
                f32x2 s1 = *(const f32x2*)(zp + 1 * 512 + row * 64 + c0);
                f32x2 s2 = *(const f32x2*)(zp + 2 * 512 + row * 64 + c0);
                f32x2 s3 = *(const f32x2*)(zp + 3 * 512 + row * 64 + c0);
                zv0 = (s0[0] + s1[0]) + (s2[0] + s3[0]);
                zv1 = (s0[1] + s1[1]) + (s2[1] + s3[1]);
            }
            float hv0 = fast_tanh(zv0 + ecur[0]);
            float hv1 = fast_tanh(zv1 + ecur[1]);
            // publish (dual): pack 2 dims + gen tag -> u64
            u32 tag = (u32)((t >> 1) & 1);
            u16 h0 = f2bf(hv0);
            u16 l0 = (u16)((f2bf(hv0 - bf2f(h0)) & 0xFFFEu) | tag);
            u16 h1 = f2bf(hv1);
            u16 l1 = (u16)((f2bf(hv1 - bf2f(h1)) & 0xFFFEu) | tag);
            u64 val = ((u64)((((u32)l1) << 16) | h1) << 32) |
                      ((((u32)l0) << 16) | h0);
            size_t po = (size_t)((t & 1) * 8 + g) * 4096 + row * 512 + s * 64 + c0;
            u64* dstf = (u64*)(h_exf + po);
            asm volatile("global_store_dwordx2 %0, %1, off sc0"
                         :: "v"(dstf), "v"(val) : "memory");
            __hip_atomic_store((u64*)(h_exs + po), val, __ATOMIC_RELAXED,
                               __HIP_MEMORY_SCOPE_AGENT);
            // h out (fp32), prefetch next e
            f32x2 hw; hw[0] = hv0; hw[1] = hv1;
            *(f32x2*)(e_io + eidx) = hw;
            if (t < 511) ecur = *(const f32x2*)(e_io + eidx + 512);
            eidx += 512;
        }
        // B2: raw barrier (zp reads consumed into registers before here)
        asm volatile("" ::: "memory");
        __builtin_amdgcn_s_barrier();
        asm volatile("" ::: "memory");
    }
}

// ---------------------------------------------------------------------------
__global__ __launch_bounds__(512) void k_ylast(const float* __restrict__ yreg,
                                               float* __restrict__ ylast) {
    int b = blockIdx.x, o = threadIdx.x;
    ylast[(size_t)b * 512 + o] = yreg[((size_t)b * 512 + 511) * 512 + o];
}

// ---------------------------------------------------------------------------
extern "C" void kernel_launch(void* const* d_in, const int* in_sizes, int n_in,
                              void* d_out, int out_size, void* d_ws, size_t ws_size,
                              hipStream_t stream) {
    const float* emb  = (const float*)d_in[0];  // [64,512,512] fp32
    const float* ll   = (const float*)d_in[1];  // [64,512]
    const float* Win  = (const float*)d_in[2];  // [512,512]
    const float* bin  = (const float*)d_in[3];  // [512]
    const float* Wy   = (const float*)d_in[4];  // [512,512]
    const float* by   = (const float*)d_in[5];  // [512]
    const float* Wout = (const float*)d_in[6];  // [512,512]
    const float* bout = (const float*)d_in[7];  // [512]

    float* out = (float*)d_out;                 // fp32 outputs
    float* h_reg = out;                         // h: [b*512+t][512]
    float* y_reg = out + (size_t)16777216;      // y: [b*512+t][512]
    float* ylast_reg = out + (size_t)33554432;  // [64][512]

    // workspace (~2.9 MB)
    char* ws = (char*)d_ws;
    size_t off = 0;
    u16* buf1 = (u16*)(ws + off); off += (size_t)512 * 512 * 2;  // shared B hi
    u16* buf2 = (u16*)(ws + off); off += (size_t)512 * 512 * 2;  // shared B lo
    u16* Mhi  = (u16*)(ws + off); off += (size_t)512 * 512 * 2;
    u16* Mlo  = (u16*)(ws + off); off += (size_t)512 * 512 * 2;
    float* z0mc  = (float*)(ws + off); off += (size_t)64 * 512 * 4;
    float* cvec  = (float*)(ws + off); off += 512 * 4;
    float* biasE = (float*)(ws + off); off += 512 * 4;
    u32* h_exf = (u32*)(ws + off); off += (size_t)2 * 8 * 4096 * 4;  // 256KB
    u32* h_exs = (u32*)(ws + off); off += (size_t)2 * 8 * 4096 * 4;  // 256KB
    int* xcd_tbl = (int*)(ws + off); off += 64 * 4;

    k_init<<<128, 256, 0, stream>>>(h_exf, xcd_tbl);  // inits BOTH buffers
    k_c<<<8, 64, 0, stream>>>(Wy, bout, bin, by, cvec, biasE);
    k_z0<<<64, 512, 0, stream>>>(ll, Wy, cvec, z0mc);
    // WoT hi/lo = transpose(W_out) split
    k_tsplit<<<dim3(16, 16), 256, 0, stream>>>(Wout, buf1, buf2);
    // M = W_y @ W_out -> bf16 hi/lo planes  (A = Wy fp32, B = WoT hi/lo)
    gemm3<<<dim3(4, 4), 256, 0, stream>>>(Wy, 1, buf1, buf2, Mhi, Mlo,
                                          nullptr, nullptr, 0);
    // Win hi/lo (reuse buffers)
    k_split<<<1024, 256, 0, stream>>>(Win, buf1, buf2);
    // e = emb @ W_in^T + (b_in + b_y + c) -> fp32 into h region
    gemm3<<<dim3(256, 4), 256, 0, stream>>>(emb, 1, buf1, buf2, nullptr, nullptr,
                                            h_reg, biasE, 1);
    // sequential scan: h region e -> h in place (fp32)
    k_scan<<<64, 256, 0, stream>>>(Mhi, Mlo, h_reg, z0mc, h_exf, h_exs, xcd_tbl);
    // Wout natural hi/lo (reuse buffers)
    k_split<<<1024, 256, 0, stream>>>(Wout, buf1, buf2);
    // y = h @ W_out^T + b_out (A = h fp32)
    gemm3<<<dim3(256, 4), 256, 0, stream>>>(h_reg, 1, buf1, buf2, nullptr, nullptr,
                                            y_reg, bout, 1);
    k_ylast<<<64, 512, 0, stream>>>(y_reg, ylast_reg);
}